// Round 11
// baseline (629.350 us; speedup 1.0000x reference)
//
#include <hip/hip_runtime.h>
#include <cstdint>
#include <cstddef>

#define U_NODES 100000
#define V_NODES 50000
#define N_EDGES 2000000
#define UBLKS ((U_NODES + 255) / 256)
#define VBLKS ((V_NODES + 255) / 256)

#define BNODES 64
#define NBUK ((U_NODES + BNODES - 1) / BNODES)   // 1563
#define HB 128
#define EPB ((N_EDGES + HB - 1) / HB)            // 15625

// dims: F=32 (u), G=32 (v), H=8 (edge); g: 72->64->32 ; f: 64->64->32 ; tail 32->1
// g_w1 rows: [0,32) u-part, [32,64) v-part, [64,72) edge-val part.

typedef _Float16 f16x8 __attribute__((ext_vector_type(8)));
typedef _Float16 f16x2 __attribute__((ext_vector_type(2)));
typedef float    f32x4 __attribute__((ext_vector_type(4)));

__device__ __forceinline__ void load8f(const float* __restrict__ p, float* x) {
    const float4* p4 = reinterpret_cast<const float4*>(p);
    float4 a = p4[0], b = p4[1];
    x[0]=a.x; x[1]=a.y; x[2]=a.z; x[3]=a.w;
    x[4]=b.x; x[5]=b.y; x[6]=b.z; x[7]=b.w;
}

__device__ __forceinline__ void load32f(const float* __restrict__ p, float* x) {
    #pragma unroll
    for (int q = 0; q < 4; ++q) load8f(p + 8*q, x + 8*q);
}

__device__ __forceinline__ unsigned pack_bf16x2(float a, float b) {
    unsigned ua = __float_as_uint(a);
    ua = (ua + 0x7FFFu + ((ua >> 16) & 1u)) >> 16;
    unsigned ub = __float_as_uint(b);
    ub = (ub + 0x7FFFu + ((ub >> 16) & 1u)) & 0xFFFF0000u;
    return ua | ub;
}

__device__ __forceinline__ unsigned pk16(float a, float b) {
    union { f16x2 h; unsigned u; } c;
    c.h[0] = (_Float16)a; c.h[1] = (_Float16)b;
    return c.u;
}
__device__ __forceinline__ float f16lo(unsigned w) {
    union { unsigned short u; _Float16 h; } c; c.u = (unsigned short)(w & 0xFFFFu);
    return (float)c.h;
}
__device__ __forceinline__ float f16hi(unsigned w) {
    union { unsigned short u; _Float16 h; } c; c.u = (unsigned short)(w >> 16);
    return (float)c.h;
}
__device__ __forceinline__ f16x8 as_f16x8(uint4 x) {
    union { uint4 u; f16x8 h; } c; c.u = x; return c.h;
}

__device__ __forceinline__ float fdot2f(unsigned a, unsigned b, float c) {
#if defined(__has_builtin) && __has_builtin(__builtin_amdgcn_fdot2)
    union { unsigned u; f16x2 h; } ca, cb; ca.u = a; cb.u = b;
    return __builtin_amdgcn_fdot2(ca.h, cb.h, c, false);
#else
    return c + f16lo(a)*f16lo(b) + f16hi(a)*f16hi(b);
#endif
}

// ---------------- pre-projection (A = u@W1u ; B = v@W1v + b1) ------------------
// NOTE (r9): keep these SEPARATE kernels — the merged dual-branch version was
// 30x slower (codegen pathology).

__global__ __launch_bounds__(256) void proj_u_kernel(
    const float* __restrict__ u, const float* __restrict__ g_w1,
    float* __restrict__ A)
{
    int n = blockIdx.x * 256 + threadIdx.x;
    if (n >= U_NODES) return;
    float x[32];
    load32f(u + (size_t)n * 32, x);
    float acc[64];
    #pragma unroll
    for (int j = 0; j < 64; ++j) acc[j] = 0.f;
    #pragma unroll
    for (int i = 0; i < 32; ++i) {
        #pragma unroll
        for (int j = 0; j < 64; ++j) acc[j] += x[i] * g_w1[i*64 + j];
    }
    float4* Ap = reinterpret_cast<float4*>(A + (size_t)n * 64);
    #pragma unroll
    for (int q = 0; q < 16; ++q)
        Ap[q] = make_float4(acc[4*q], acc[4*q+1], acc[4*q+2], acc[4*q+3]);
}

__global__ __launch_bounds__(256) void proj_v_kernel(
    const float* __restrict__ v, const float* __restrict__ g_w1,
    const float* __restrict__ g_b1, float* __restrict__ B)
{
    int n = blockIdx.x * 256 + threadIdx.x;
    if (n >= V_NODES) return;
    float x[32];
    load32f(v + (size_t)n * 32, x);
    float acc[64];
    #pragma unroll
    for (int j = 0; j < 64; ++j) acc[j] = g_b1[j];
    #pragma unroll
    for (int i = 0; i < 32; ++i) {
        #pragma unroll
        for (int j = 0; j < 64; ++j) acc[j] += x[i] * g_w1[(32+i)*64 + j];
    }
    float4* Bp = reinterpret_cast<float4*>(B + (size_t)n * 64);
    #pragma unroll
    for (int q = 0; q < 16; ++q)
        Bp[q] = make_float4(acc[4*q], acc[4*q+1], acc[4*q+2], acc[4*q+3]);
}

// ---------------- bucket CSR build (64-node buckets) ---------------------------

// phase 1: per-block LDS histogram -> ~200K global atomics (vs 2M in rank)
__global__ __launch_bounds__(1024) void bucket_hist_kernel(
    const int* __restrict__ e_dst, int* __restrict__ bucketcnt,
    int* __restrict__ blockbase)
{
    __shared__ int hist[NBUK];
    const int tid = threadIdx.x, blk = blockIdx.x;
    for (int i = tid; i < NBUK; i += 1024) hist[i] = 0;
    __syncthreads();
    int e0 = blk * EPB;
    int e1 = e0 + EPB; if (e1 > N_EDGES) e1 = N_EDGES;
    for (int e = e0 + tid; e < e1; e += 1024)
        atomicAdd(&hist[e_dst[e] >> 6], 1);
    __syncthreads();
    for (int b = tid; b < NBUK; b += 1024) {
        int c = hist[b];
        blockbase[blk * NBUK + b] = c ? atomicAdd(&bucketcnt[b], c) : 0;
    }
}

// scan trio (reused for n = NBUK)
__global__ __launch_bounds__(256) void scan_block_kernel(
    const int* __restrict__ deg, int* __restrict__ off, int* __restrict__ aux, int n)
{
    __shared__ int s[256];
    int tid = threadIdx.x;
    int i = blockIdx.x * 256 + tid;
    int x = (i < n) ? deg[i] : 0;
    s[tid] = x;
    __syncthreads();
    #pragma unroll
    for (int o = 1; o < 256; o <<= 1) {
        int t = (tid >= o) ? s[tid - o] : 0;
        __syncthreads();
        s[tid] += t;
        __syncthreads();
    }
    if (i < n) off[i + 1] = s[tid];
    if (tid == 255) aux[blockIdx.x] = s[255];
}

__global__ __launch_bounds__(512) void scan_aux_kernel(int* __restrict__ aux, int nA)
{
    __shared__ int s[512];
    int tid = threadIdx.x;
    int x = (tid < nA) ? aux[tid] : 0;
    s[tid] = x;
    __syncthreads();
    #pragma unroll
    for (int o = 1; o < 512; o <<= 1) {
        int t = (tid >= o) ? s[tid - o] : 0;
        __syncthreads();
        s[tid] += t;
        __syncthreads();
    }
    if (tid < nA) aux[tid] = s[tid] - x;  // exclusive
}

__global__ __launch_bounds__(256) void scan_add_kernel(
    int* __restrict__ off, const int* __restrict__ aux, int n)
{
    int i = blockIdx.x * 256 + threadIdx.x;
    if (i == 0) off[0] = 0;
    if (i < n) off[i + 1] += aux[i >> 8];
}

// phase 3: rank via LDS cursors (2M LDS atomics, ~0 global atomics) + pack 32B rec
__global__ __launch_bounds__(1024) void bucket_pack_kernel(
    const int* __restrict__ e_dst, const int* __restrict__ e_src,
    const float* __restrict__ e_vals, const int* __restrict__ bucket_off,
    const int* __restrict__ blockbase, unsigned* __restrict__ epk)
{
    __shared__ int cur[NBUK];
    __shared__ int base[NBUK];
    const int tid = threadIdx.x, blk = blockIdx.x;
    for (int i = tid; i < NBUK; i += 1024) {
        cur[i] = 0;
        base[i] = bucket_off[i] + blockbase[blk * NBUK + i];
    }
    __syncthreads();
    int e0 = blk * EPB;
    int e1 = e0 + EPB; if (e1 > N_EDGES) e1 = N_EDGES;
    for (int e = e0 + tid; e < e1; e += 1024) {
        int d = e_dst[e];
        int b = d >> 6;
        int lr = atomicAdd(&cur[b], 1);
        int pos = base[b] + lr;
        float ev[8];
        load8f(e_vals + (size_t)e * 8, ev);
        uint4 w0;
        w0.x = (unsigned)d;
        w0.y = (unsigned)e_src[e];
        w0.z = pk16(ev[0], ev[1]);
        w0.w = pk16(ev[2], ev[3]);
        uint2 w1;
        w1.x = pk16(ev[4], ev[5]);
        w1.y = pk16(ev[6], ev[7]);
        unsigned* dst = epk + (size_t)pos * 8;
        *reinterpret_cast<uint4*>(dst)     = w0;
        *reinterpret_cast<uint2*>(dst + 4) = w1;
    }
}

// ---------------- bucket edge kernel: fragment-direct h1 + MFMA W2
//                  + LDS-privatized f32 aggregation (no sort-walk, no barriers
//                  pairs, 1 barrier/tile via double-buffered s_dl) -------------

__device__ __forceinline__ void load_recs_b(
    const unsigned* __restrict__ epk, int beg, int cnt, int t, int wv, int lm,
    int* dM, int* sM, unsigned (*evp)[4])
{
    #pragma unroll
    for (int mt = 0; mt < 4; ++mt) {
        int rel = t*256 + wv*64 + mt*16 + lm;
        if (rel < cnt) {
            const unsigned* ep = epk + (size_t)(beg + rel) * 8;
            uint4 w0 = *reinterpret_cast<const uint4*>(ep);
            uint2 w1 = *reinterpret_cast<const uint2*>(ep + 4);
            dM[mt] = (int)w0.x; sM[mt] = (int)w0.y;
            evp[mt][0] = w0.z; evp[mt][1] = w0.w; evp[mt][2] = w1.x; evp[mt][3] = w1.y;
        } else {
            dM[mt] = -1; sM[mt] = 0;
            evp[mt][0] = evp[mt][1] = evp[mt][2] = evp[mt][3] = 0;
        }
    }
}

__global__ __launch_bounds__(256) void edge_agg_kernel(
    const float* __restrict__ A, const float* __restrict__ B,
    const unsigned* __restrict__ epk, const int* __restrict__ bucket_off,
    const float* __restrict__ g_w1, const float* __restrict__ g_w2,
    const float* __restrict__ g_b2, float* __restrict__ agg)
{
    __shared__ float s_agg[BNODES * 33];                // 8448 B, f32
    __shared__ unsigned s_w2[32 * 33];                  // 4224 B
    __shared__ __align__(16) unsigned s_w1e[4 * 64];    // 1024 B
    __shared__ int s_dl[2][256];                        // 2048 B

    const int tid = threadIdx.x;
    const int bk  = blockIdx.x;
    const int beg = bucket_off[bk];
    const int cnt = bucket_off[bk + 1] - beg;
    const int node0 = bk * BNODES;

    // stage W2 / W1e as f16 pairs; zero s_agg
    #pragma unroll
    for (int i = 0; i < 4; ++i) {
        int idx = tid + i * 256;
        int kp = idx >> 5, n = idx & 31;
        s_w2[kp * 33 + n] = pk16(g_w2[(2*kp)*32 + n], g_w2[(2*kp+1)*32 + n]);
    }
    {
        int i2 = tid >> 6, c = tid & 63;
        s_w1e[i2 * 64 + c] = pk16(g_w1[(64 + 2*i2)*64 + c], g_w1[(64 + 2*i2 + 1)*64 + c]);
    }
    for (int i = tid; i < BNODES * 33; i += 256) s_agg[i] = 0.f;

    const int wv   = tid >> 6;
    const int lane = tid & 63;
    const int lm   = lane & 15;
    const int lg   = lane >> 4;
    const float b2a = g_b2[lm], b2b = g_b2[16 + lm];

    const int nt = (cnt + 255) >> 8;
    int dC[4], sC[4]; unsigned evC[4][4];
    if (nt > 0) load_recs_b(epk, beg, cnt, 0, wv, lm, dC, sC, evC);
    __syncthreads();   // weights + zeros ready

    for (int t = 0; t < nt; ++t) {
        // ---- h1 in MFMA A-fragment registers ----
        uint4 afr[4][2];
        #pragma unroll
        for (int kt = 0; kt < 2; ++kt) {
            float acc[4][8];
            #pragma unroll
            for (int mt = 0; mt < 4; ++mt) {
                if (dC[mt] >= 0) {
                    const float4* Ap = reinterpret_cast<const float4*>(A + (size_t)dC[mt]*64 + kt*32 + lg*8);
                    const float4* Bp = reinterpret_cast<const float4*>(B + (size_t)sC[mt]*64 + kt*32 + lg*8);
                    float4 a0 = Ap[0], a1 = Ap[1], b0 = Bp[0], b1 = Bp[1];
                    acc[mt][0] = a0.x + b0.x; acc[mt][1] = a0.y + b0.y;
                    acc[mt][2] = a0.z + b0.z; acc[mt][3] = a0.w + b0.w;
                    acc[mt][4] = a1.x + b1.x; acc[mt][5] = a1.y + b1.y;
                    acc[mt][6] = a1.z + b1.z; acc[mt][7] = a1.w + b1.w;
                } else {
                    #pragma unroll
                    for (int j = 0; j < 8; ++j) acc[mt][j] = 0.f;
                }
            }
            #pragma unroll
            for (int i2 = 0; i2 < 4; ++i2) {
                uint4 wA = *reinterpret_cast<const uint4*>(&s_w1e[i2*64 + kt*32 + lg*8]);
                uint4 wB = *reinterpret_cast<const uint4*>(&s_w1e[i2*64 + kt*32 + lg*8 + 4]);
                #pragma unroll
                for (int mt = 0; mt < 4; ++mt) {
                    unsigned e2 = evC[mt][i2];
                    acc[mt][0] = fdot2f(e2, wA.x, acc[mt][0]);
                    acc[mt][1] = fdot2f(e2, wA.y, acc[mt][1]);
                    acc[mt][2] = fdot2f(e2, wA.z, acc[mt][2]);
                    acc[mt][3] = fdot2f(e2, wA.w, acc[mt][3]);
                    acc[mt][4] = fdot2f(e2, wB.x, acc[mt][4]);
                    acc[mt][5] = fdot2f(e2, wB.y, acc[mt][5]);
                    acc[mt][6] = fdot2f(e2, wB.z, acc[mt][6]);
                    acc[mt][7] = fdot2f(e2, wB.w, acc[mt][7]);
                }
            }
            #pragma unroll
            for (int mt = 0; mt < 4; ++mt) {
                uint4 w;
                w.x = pk16(fmaxf(acc[mt][0], 0.f), fmaxf(acc[mt][1], 0.f));
                w.y = pk16(fmaxf(acc[mt][2], 0.f), fmaxf(acc[mt][3], 0.f));
                w.z = pk16(fmaxf(acc[mt][4], 0.f), fmaxf(acc[mt][5], 0.f));
                w.w = pk16(fmaxf(acc[mt][6], 0.f), fmaxf(acc[mt][7], 0.f));
                afr[mt][kt] = w;
            }
        }

        // ---- MFMA: [64 edges x 64] @ [64 x 32] ----
        f32x4 mac[4][2];
        #pragma unroll
        for (int mt = 0; mt < 4; ++mt) {
            #pragma unroll
            for (int nt2 = 0; nt2 < 2; ++nt2) {
                mac[mt][nt2][0] = 0.f; mac[mt][nt2][1] = 0.f;
                mac[mt][nt2][2] = 0.f; mac[mt][nt2][3] = 0.f;
            }
        }
        #pragma unroll
        for (int kt = 0; kt < 2; ++kt) {
            uint4 bf0, bf1;
            int kp = kt*16 + lg*4;
            bf0.x = s_w2[(kp+0)*33 + lm];      bf1.x = s_w2[(kp+0)*33 + 16 + lm];
            bf0.y = s_w2[(kp+1)*33 + lm];      bf1.y = s_w2[(kp+1)*33 + 16 + lm];
            bf0.z = s_w2[(kp+2)*33 + lm];      bf1.z = s_w2[(kp+2)*33 + 16 + lm];
            bf0.w = s_w2[(kp+3)*33 + lm];      bf1.w = s_w2[(kp+3)*33 + 16 + lm];
            f16x8 b0 = as_f16x8(bf0), b1 = as_f16x8(bf1);
            #pragma unroll
            for (int mt = 0; mt < 4; ++mt) {
                f16x8 a = as_f16x8(afr[mt][kt]);
                mac[mt][0] = __builtin_amdgcn_mfma_f32_16x16x32_f16(a, b0, mac[mt][0], 0, 0, 0);
                mac[mt][1] = __builtin_amdgcn_mfma_f32_16x16x32_f16(a, b1, mac[mt][1], 0, 0, 0);
            }
        }

        // publish this tile's d per row (double-buffered; one barrier per tile)
        if (lg == 0) {
            #pragma unroll
            for (int mt = 0; mt < 4; ++mt) s_dl[t & 1][wv*64 + mt*16 + lm] = dC[mt];
        }
        __syncthreads();

        // prefetch next tile's records (overlaps with the ds_add phase)
        if (t + 1 < nt) load_recs_b(epk, beg, cnt, t + 1, wv, lm, dC, sC, evC);

        // gather d for my D-layout rows, then privatized LDS aggregation
        #pragma unroll
        for (int mt = 0; mt < 4; ++mt) {
            #pragma unroll
            for (int r = 0; r < 4; ++r) {
                int dd = s_dl[t & 1][wv*64 + mt*16 + lg*4 + r];
                if (dd >= 0) {
                    int loc = (dd & (BNODES - 1)) * 33;
                    atomicAdd(&s_agg[loc + lm],      fmaxf(mac[mt][0][r] + b2a, 0.f));
                    atomicAdd(&s_agg[loc + 16 + lm], fmaxf(mac[mt][1][r] + b2b, 0.f));
                }
            }
        }
    }
    __syncthreads();

    // store bucket's agg (exclusive owner, coalesced, covers all 64 nodes)
    for (int i = tid; i < BNODES * 32; i += 256) {
        int n = node0 + (i >> 5);
        if (n < U_NODES) agg[(size_t)n * 32 + (i & 31)] = s_agg[(i >> 5) * 33 + (i & 31)];
    }
}

// ---------------- node MLP (reads agg) -----------------------------------------

__global__ __launch_bounds__(256) void node_kernel(
    const float* __restrict__ u, const float* __restrict__ agg,
    const float* __restrict__ f_w1, const float* __restrict__ f_b1,
    const float* __restrict__ f_w2, const float* __restrict__ f_b2,
    const float* __restrict__ t_w, const float* __restrict__ t_b,
    float* __restrict__ out)
{
    int n = blockIdx.x * 256 + threadIdx.x;
    if (n >= U_NODES) return;
    float x[64];
    load32f(u   + (size_t)n * 32, x);
    load32f(agg + (size_t)n * 32, x + 32);
    float z1[64];
    #pragma unroll
    for (int j = 0; j < 64; ++j) z1[j] = f_b1[j];
    #pragma unroll
    for (int i = 0; i < 64; ++i) {
        #pragma unroll
        for (int j = 0; j < 64; ++j) z1[j] += x[i] * f_w1[i*64 + j];
    }
    #pragma unroll
    for (int j = 0; j < 64; ++j) z1[j] = fmaxf(z1[j], 0.f);
    float z2[32];
    #pragma unroll
    for (int k = 0; k < 32; ++k) z2[k] = f_b2[k];
    #pragma unroll
    for (int j = 0; j < 64; ++j) {
        #pragma unroll
        for (int k = 0; k < 32; ++k) z2[k] += z1[j] * f_w2[j*32 + k];
    }
    #pragma unroll
    for (int k = 0; k < 32; ++k) z2[k] = fmaxf(z2[k], 0.f);
    float o = t_b[0];
    #pragma unroll
    for (int k = 0; k < 32; ++k) o += z2[k] * t_w[k];
    out[n] = 1.f / (1.f + expf(-o));
}

// ---------------- fallbacks for small workspaces -------------------------------

__global__ __launch_bounds__(256) void rank_kernel(
    const int* __restrict__ e_dst, int* __restrict__ deg, int* __restrict__ rank)
{
    int e = blockIdx.x * 256 + threadIdx.x;
    if (e >= N_EDGES) return;
    rank[e] = atomicAdd(&deg[e_dst[e]], 1);
}

__global__ __launch_bounds__(256) void scatter_kernel(
    const int* __restrict__ e_dst, const int* __restrict__ off,
    const int* __restrict__ rank, int* __restrict__ sorted_eid)
{
    int e = blockIdx.x * 256 + threadIdx.x;
    if (e >= N_EDGES) return;
    int d = e_dst[e];
    sorted_eid[off[d] + rank[e]] = e;
}

template <bool HAS_A, bool HAS_B>
__global__ __launch_bounds__(256) void edge_sorted_kernel(
    const float* __restrict__ A, const float* __restrict__ B,
    const float* __restrict__ u, const float* __restrict__ v,
    const float* __restrict__ e_vals, const int* __restrict__ e_src,
    const int* __restrict__ e_dst, const int* __restrict__ seid,
    const float* __restrict__ g_w1, const float* __restrict__ g_b1,
    const float* __restrict__ g_w2, const float* __restrict__ g_b2,
    float* __restrict__ agg)
{
    __shared__ unsigned lds_h[256][17];
    __shared__ int lds_d[256];
    __shared__ int lds_heads[256];
    __shared__ int lds_cnt;
    __shared__ int lds_prev_d, lds_next_d;

    const int tid = threadIdx.x;
    const long p = (long)blockIdx.x * 256 + tid;

    if (tid == 0) {
        lds_cnt = 0;
        long pprev = (long)blockIdx.x * 256 - 1;
        lds_prev_d = (pprev < 0) ? -2 : e_dst[seid[pprev]];
        long pnext = (long)blockIdx.x * 256 + 256;
        lds_next_d = (pnext >= N_EDGES) ? -2 : e_dst[seid[pnext]];
    }

    int d = -1;
    if (p < N_EDGES) {
        int eid = seid[p];
        d = e_dst[eid];
        int s = e_src[eid];

        float h1[64];
        if constexpr (HAS_A) {
            const float4* Ap = reinterpret_cast<const float4*>(A + (size_t)d * 64);
            #pragma unroll
            for (int q = 0; q < 16; ++q) {
                float4 a = Ap[q];
                h1[4*q+0] = a.x; h1[4*q+1] = a.y; h1[4*q+2] = a.z; h1[4*q+3] = a.w;
            }
        } else {
            #pragma unroll
            for (int j = 0; j < 64; ++j) h1[j] = 0.f;
            float x[32];
            load32f(u + (size_t)d * 32, x);
            #pragma unroll
            for (int i = 0; i < 32; ++i) {
                #pragma unroll
                for (int j = 0; j < 64; ++j) h1[j] += x[i] * g_w1[i*64 + j];
            }
        }
        if constexpr (HAS_B) {
            const float4* Bp = reinterpret_cast<const float4*>(B + (size_t)s * 64);
            #pragma unroll
            for (int q = 0; q < 16; ++q) {
                float4 b = Bp[q];
                h1[4*q+0] += b.x; h1[4*q+1] += b.y; h1[4*q+2] += b.z; h1[4*q+3] += b.w;
            }
        } else {
            #pragma unroll
            for (int j = 0; j < 64; ++j) h1[j] += g_b1[j];
            float x[32];
            load32f(v + (size_t)s * 32, x);
            #pragma unroll
            for (int i = 0; i < 32; ++i) {
                #pragma unroll
                for (int j = 0; j < 64; ++j) h1[j] += x[i] * g_w1[(32+i)*64 + j];
            }
        }
        float ev[8];
        load8f(e_vals + (size_t)eid * 8, ev);
        #pragma unroll
        for (int i = 0; i < 8; ++i) {
            #pragma unroll
            for (int j = 0; j < 64; ++j) h1[j] += ev[i] * g_w1[(64+i)*64 + j];
        }
        #pragma unroll
        for (int j = 0; j < 64; ++j) h1[j] = fmaxf(h1[j], 0.f);

        float h2[32];
        #pragma unroll
        for (int k = 0; k < 32; ++k) h2[k] = g_b2[k];
        #pragma unroll
        for (int i = 0; i < 64; ++i) {
            #pragma unroll
            for (int k = 0; k < 32; ++k) h2[k] += h1[i] * g_w2[i*32 + k];
        }
        #pragma unroll
        for (int cp = 0; cp < 16; ++cp)
            lds_h[tid][cp] = pack_bf16x2(fmaxf(h2[2*cp], 0.f), fmaxf(h2[2*cp+1], 0.f));
    }
    lds_d[tid] = d;
    __syncthreads();

    if (p < N_EDGES) {
        int prevd = (tid == 0) ? lds_prev_d : lds_d[tid - 1];
        bool true_head = (prevd != d);
        bool is_head = (tid == 0) || true_head;
        if (is_head) {
            int idx = atomicAdd(&lds_cnt, 1);
            lds_heads[idx] = tid | (true_head ? 0x10000 : 0);
        }
    }
    __syncthreads();

    const int nseg = lds_cnt;
    const int next_d = lds_next_d;
    for (int w = tid; w < nseg * 16; w += 256) {
        int seg = w >> 4, cp = w & 15;
        int ent = lds_heads[seg];
        int h = ent & 0xFFFF;
        bool thead = (ent & 0x10000) != 0;
        int dd = lds_d[h];
        float s0 = 0.f, s1 = 0.f;
        int r = h;
        while (r < 256 && lds_d[r] == dd) {
            unsigned x = lds_h[r][cp];
            s0 += __uint_as_float(x << 16);
            s1 += __uint_as_float(x & 0xFFFF0000u);
            ++r;
        }
        bool end_complete = (r < 256) || (next_d != dd);
        float* dst = agg + (size_t)dd * 32 + 2 * cp;
        if (thead && end_complete) {
            *reinterpret_cast<float2*>(dst) = make_float2(s0, s1);
        } else {
            atomicAdd(dst + 0, s0);
            atomicAdd(dst + 1, s1);
        }
    }
}

__global__ __launch_bounds__(256) void edge_direct_kernel(
    const float* __restrict__ u, const float* __restrict__ v,
    const float* __restrict__ e_vals, const int* __restrict__ e_src,
    const int* __restrict__ e_dst, const float* __restrict__ g_w1,
    const float* __restrict__ g_b1, const float* __restrict__ g_w2,
    const float* __restrict__ g_b2, float* __restrict__ agg)
{
    int e = blockIdx.x * 256 + threadIdx.x;
    if (e >= N_EDGES) return;
    int d = e_dst[e];
    int s = e_src[e];
    float x[72];
    load32f(u + (size_t)d * 32, x);
    load32f(v + (size_t)s * 32, x + 32);
    load8f(e_vals + (size_t)e * 8, x + 64);
    float h1[64];
    #pragma unroll
    for (int j = 0; j < 64; ++j) h1[j] = g_b1[j];
    #pragma unroll
    for (int i = 0; i < 72; ++i) {
        #pragma unroll
        for (int j = 0; j < 64; ++j) h1[j] += x[i] * g_w1[i*64 + j];
    }
    #pragma unroll
    for (int j = 0; j < 64; ++j) h1[j] = fmaxf(h1[j], 0.f);
    float acc2[32];
    #pragma unroll
    for (int k = 0; k < 32; ++k) acc2[k] = g_b2[k];
    #pragma unroll
    for (int i = 0; i < 64; ++i) {
        #pragma unroll
        for (int k = 0; k < 32; ++k) acc2[k] += h1[i] * g_w2[i*32 + k];
    }
    float* aggp = agg + (size_t)d * 32;
    #pragma unroll
    for (int k = 0; k < 32; ++k) atomicAdd(aggp + k, fmaxf(acc2[k], 0.f));
}

// ---------------- launch -------------------------------------------------------

static inline size_t align256(size_t x) { return (x + 255) & ~(size_t)255; }

extern "C" void kernel_launch(void* const* d_in, const int* in_sizes, int n_in,
                              void* d_out, int out_size, void* d_ws, size_t ws_size,
                              hipStream_t stream) {
    const float* u      = (const float*)d_in[0];
    const float* v      = (const float*)d_in[1];
    const float* e_vals = (const float*)d_in[2];
    const int*   e_src  = (const int*)  d_in[3];
    const int*   e_dst  = (const int*)  d_in[4];
    const float* g_w1   = (const float*)d_in[5];
    const float* g_b1   = (const float*)d_in[6];
    const float* g_w2   = (const float*)d_in[7];
    const float* g_b2   = (const float*)d_in[8];
    const float* f_w1   = (const float*)d_in[9];
    const float* f_b1   = (const float*)d_in[10];
    const float* f_w2   = (const float*)d_in[11];
    const float* f_b2   = (const float*)d_in[12];
    const float* t_w    = (const float*)d_in[13];
    const float* t_b    = (const float*)d_in[14];
    float* out = (float*)d_out;

    char* wsc = (char*)d_ws;
    const int eBlocks = (N_EDGES + 255) / 256;
    const int nChunksB = (NBUK + 255) / 256;                      // 7

    const size_t bcB   = align256((size_t)NBUK * 4);              // 6.3 KB
    const size_t boB   = align256((size_t)(NBUK + 1) * 4);
    const size_t auxB  = align256((size_t)nChunksB * 4);
    const size_t bbB   = align256((size_t)HB * NBUK * 4);         // 800 KB
    const size_t aggB  = align256((size_t)U_NODES * 32 * 4);      // 12.8 MB
    const size_t epkB  = align256((size_t)N_EDGES * 32);          // 64 MB
    const size_t bB    = align256((size_t)V_NODES * 64 * 4);      // 12.8 MB
    const size_t aB    = align256((size_t)U_NODES * 64 * 4);      // 25.6 MB
    const size_t e4B   = align256((size_t)N_EDGES * 4);           // 8 MB

    // new bucket-path layout (~116 MB)
    size_t o = 0;
    size_t oBc  = o; o += bcB;
    size_t oBo  = o; o += boB;
    size_t oAux = o; o += auxB;
    size_t oBb  = o; o += bbB;
    size_t oAgg = o; o += aggB;
    size_t oEp  = o; o += epkB;
    size_t oBn  = o; o += bB;
    size_t oAn  = o; o += aB;
    size_t needNew = o;

    // old fallback layout
    const size_t degB = align256((size_t)U_NODES * 4);
    const size_t offB = align256((size_t)(U_NODES + 1) * 4);
    const int nChunksU = (U_NODES + 255) / 256;                   // 391
    const size_t auxUB = align256((size_t)nChunksU * 4);
    size_t o3 = 0;
    size_t oDeg3 = o3; o3 += degB;
    size_t oOff3 = o3; o3 += offB;
    size_t oAux3 = o3; o3 += auxUB;
    size_t oAgg3 = o3; o3 += aggB;
    size_t oSeid = o3; o3 += e4B;
    size_t needT4 = o3 + e4B;                                     // +rank
    size_t oB3 = o3;   o3 += bB;
    size_t oA3 = o3;   o3 += aB;
    size_t needT3 = o3;                                           // rank aliases A3

    if (ws_size >= needNew) {
        int* bucketcnt = (int*)(wsc + oBc);
        int* bucketoff = (int*)(wsc + oBo);
        int* aux       = (int*)(wsc + oAux);
        int* blockbase = (int*)(wsc + oBb);
        float* agg     = (float*)(wsc + oAgg);
        unsigned* epk  = (unsigned*)(wsc + oEp);
        float* B       = (float*)(wsc + oBn);
        float* A       = (float*)(wsc + oAn);

        hipMemsetAsync(bucketcnt, 0, (size_t)NBUK * 4, stream);

        bucket_hist_kernel<<<HB, 1024, 0, stream>>>(e_dst, bucketcnt, blockbase);
        scan_block_kernel<<<nChunksB, 256, 0, stream>>>(bucketcnt, bucketoff, aux, NBUK);
        scan_aux_kernel<<<1, 512, 0, stream>>>(aux, nChunksB);
        scan_add_kernel<<<nChunksB, 256, 0, stream>>>(bucketoff, aux, NBUK);
        bucket_pack_kernel<<<HB, 1024, 0, stream>>>(e_dst, e_src, e_vals,
                                                    bucketoff, blockbase, epk);
        proj_v_kernel<<<VBLKS, 256, 0, stream>>>(v, g_w1, g_b1, B);
        proj_u_kernel<<<UBLKS, 256, 0, stream>>>(u, g_w1, A);
        edge_agg_kernel<<<NBUK, 256, 0, stream>>>(A, B, epk, bucketoff,
                                                  g_w1, g_w2, g_b2, agg);
        node_kernel<<<UBLKS, 256, 0, stream>>>(
            u, agg, f_w1, f_b1, f_w2, f_b2, t_w, t_b, out);
    } else if (ws_size >= needT4) {
        const bool hasAB = (ws_size >= needT3);
        int* deg   = (int*)(wsc + oDeg3);
        int* off   = (int*)(wsc + oOff3);
        int* aux   = (int*)(wsc + oAux3);
        float* agg = (float*)(wsc + oAgg3);
        int* seid  = (int*)(wsc + oSeid);
        float* B = hasAB ? (float*)(wsc + oB3) : nullptr;
        float* A = hasAB ? (float*)(wsc + oA3) : nullptr;
        int* rank = hasAB ? (int*)A : (int*)(wsc + oSeid + e4B);

        hipMemsetAsync(deg, 0, (size_t)U_NODES * 4, stream);
        hipMemsetAsync(agg, 0, (size_t)U_NODES * 32 * 4, stream);

        rank_kernel<<<eBlocks, 256, 0, stream>>>(e_dst, deg, rank);
        scan_block_kernel<<<nChunksU, 256, 0, stream>>>(deg, off, aux, U_NODES);
        scan_aux_kernel<<<1, 512, 0, stream>>>(aux, nChunksU);
        scan_add_kernel<<<nChunksU, 256, 0, stream>>>(off, aux, U_NODES);
        scatter_kernel<<<eBlocks, 256, 0, stream>>>(e_dst, off, rank, seid);

        if (hasAB) {
            proj_v_kernel<<<VBLKS, 256, 0, stream>>>(v, g_w1, g_b1, B);
            proj_u_kernel<<<UBLKS, 256, 0, stream>>>(u, g_w1, A);
            edge_sorted_kernel<true, true><<<eBlocks, 256, 0, stream>>>(
                A, B, u, v, e_vals, e_src, e_dst, seid, g_w1, g_b1, g_w2, g_b2, agg);
        } else {
            edge_sorted_kernel<false, false><<<eBlocks, 256, 0, stream>>>(
                nullptr, nullptr, u, v, e_vals, e_src, e_dst, seid,
                g_w1, g_b1, g_w2, g_b2, agg);
        }
        node_kernel<<<UBLKS, 256, 0, stream>>>(
            u, agg, f_w1, f_b1, f_w2, f_b2, t_w, t_b, out);
    } else {
        float* agg0 = (float*)wsc;
        hipMemsetAsync(agg0, 0, (size_t)U_NODES * 32 * 4, stream);
        edge_direct_kernel<<<eBlocks, 256, 0, stream>>>(
            u, v, e_vals, e_src, e_dst, g_w1, g_b1, g_w2, g_b2, agg0);
        node_kernel<<<UBLKS, 256, 0, stream>>>(
            u, agg0, f_w1, f_b1, f_w2, f_b2, t_w, t_b, out);
    }
}

// Round 12
// 403.520 us; speedup vs baseline: 1.5597x; 1.5597x over previous
//
#include <hip/hip_runtime.h>
#include <cstdint>
#include <cstddef>

#define U_NODES 100000
#define V_NODES 50000
#define N_EDGES 2000000
#define UBLKS ((U_NODES + 255) / 256)
#define VBLKS ((V_NODES + 255) / 256)

#define BNODES 64
#define NBUK ((U_NODES + BNODES - 1) / BNODES)   // 1563
#define SCAP_PT 7
#define SCAP (SCAP_PT * 256)                     // 1792 records/bucket capacity
#define DFLAG 0x10000000

// dims: F=32 (u), G=32 (v), H=8 (edge); g: 72->64->32 ; f: 64->64->32 ; tail 32->1
// g_w1 rows: [0,32) u-part, [32,64) v-part, [64,72) edge-val part.

typedef _Float16 f16x8 __attribute__((ext_vector_type(8)));
typedef _Float16 f16x2 __attribute__((ext_vector_type(2)));
typedef float    f32x4 __attribute__((ext_vector_type(4)));

__device__ __forceinline__ void load8f(const float* __restrict__ p, float* x) {
    const float4* p4 = reinterpret_cast<const float4*>(p);
    float4 a = p4[0], b = p4[1];
    x[0]=a.x; x[1]=a.y; x[2]=a.z; x[3]=a.w;
    x[4]=b.x; x[5]=b.y; x[6]=b.z; x[7]=b.w;
}

__device__ __forceinline__ void load32f(const float* __restrict__ p, float* x) {
    #pragma unroll
    for (int q = 0; q < 4; ++q) load8f(p + 8*q, x + 8*q);
}

__device__ __forceinline__ unsigned pack_bf16x2(float a, float b) {
    unsigned ua = __float_as_uint(a);
    ua = (ua + 0x7FFFu + ((ua >> 16) & 1u)) >> 16;
    unsigned ub = __float_as_uint(b);
    ub = (ub + 0x7FFFu + ((ub >> 16) & 1u)) & 0xFFFF0000u;
    return ua | ub;
}
__device__ __forceinline__ unsigned short bf16_1(float a) {
    unsigned ua = __float_as_uint(a);
    return (unsigned short)((ua + 0x7FFFu + ((ua >> 16) & 1u)) >> 16);
}

__device__ __forceinline__ unsigned pk16(float a, float b) {
    union { f16x2 h; unsigned u; } c;
    c.h[0] = (_Float16)a; c.h[1] = (_Float16)b;
    return c.u;
}
__device__ __forceinline__ float f16lo(unsigned w) {
    union { unsigned short u; _Float16 h; } c; c.u = (unsigned short)(w & 0xFFFFu);
    return (float)c.h;
}
__device__ __forceinline__ float f16hi(unsigned w) {
    union { unsigned short u; _Float16 h; } c; c.u = (unsigned short)(w >> 16);
    return (float)c.h;
}
__device__ __forceinline__ f16x8 as_f16x8(uint4 x) {
    union { uint4 u; f16x8 h; } c; c.u = x; return c.h;
}

__device__ __forceinline__ float fdot2f(unsigned a, unsigned b, float c) {
#if defined(__has_builtin) && __has_builtin(__builtin_amdgcn_fdot2)
    union { unsigned u; f16x2 h; } ca, cb; ca.u = a; cb.u = b;
    return __builtin_amdgcn_fdot2(ca.h, cb.h, c, false);
#else
    return c + f16lo(a)*f16lo(b) + f16hi(a)*f16hi(b);
#endif
}

// ---------------- pre-projection (A = u@W1u ; B = v@W1v + b1) ------------------
// NOTE (r9): keep these SEPARATE kernels — merged dual-branch was 30x slower.

__global__ __launch_bounds__(256) void proj_u_kernel(
    const float* __restrict__ u, const float* __restrict__ g_w1,
    float* __restrict__ A)
{
    int n = blockIdx.x * 256 + threadIdx.x;
    if (n >= U_NODES) return;
    float x[32];
    load32f(u + (size_t)n * 32, x);
    float acc[64];
    #pragma unroll
    for (int j = 0; j < 64; ++j) acc[j] = 0.f;
    #pragma unroll
    for (int i = 0; i < 32; ++i) {
        #pragma unroll
        for (int j = 0; j < 64; ++j) acc[j] += x[i] * g_w1[i*64 + j];
    }
    float4* Ap = reinterpret_cast<float4*>(A + (size_t)n * 64);
    #pragma unroll
    for (int q = 0; q < 16; ++q)
        Ap[q] = make_float4(acc[4*q], acc[4*q+1], acc[4*q+2], acc[4*q+3]);
}

__global__ __launch_bounds__(256) void proj_v_kernel(
    const float* __restrict__ v, const float* __restrict__ g_w1,
    const float* __restrict__ g_b1, float* __restrict__ B)
{
    int n = blockIdx.x * 256 + threadIdx.x;
    if (n >= V_NODES) return;
    float x[32];
    load32f(v + (size_t)n * 32, x);
    float acc[64];
    #pragma unroll
    for (int j = 0; j < 64; ++j) acc[j] = g_b1[j];
    #pragma unroll
    for (int i = 0; i < 32; ++i) {
        #pragma unroll
        for (int j = 0; j < 64; ++j) acc[j] += x[i] * g_w1[(32+i)*64 + j];
    }
    float4* Bp = reinterpret_cast<float4*>(B + (size_t)n * 64);
    #pragma unroll
    for (int q = 0; q < 16; ++q)
        Bp[q] = make_float4(acc[4*q], acc[4*q+1], acc[4*q+2], acc[4*q+3]);
}

// ---------------- bucket CSR build (64-node buckets) ---------------------------

// per-block LDS histogram -> ~NBUK*nblk global atomics (vs 2M per-node rank)
__global__ __launch_bounds__(1024) void bucket_hist_kernel(
    const int* __restrict__ e_dst, int* __restrict__ bucketcnt,
    int* __restrict__ blockbase, int epb)
{
    __shared__ int hist[NBUK];
    const int tid = threadIdx.x, blk = blockIdx.x;
    for (int i = tid; i < NBUK; i += 1024) hist[i] = 0;
    __syncthreads();
    int e0 = blk * epb;
    int e1 = e0 + epb; if (e1 > N_EDGES) e1 = N_EDGES;
    for (int e = e0 + tid; e < e1; e += 1024)
        atomicAdd(&hist[e_dst[e] >> 6], 1);
    __syncthreads();
    for (int b = tid; b < NBUK; b += 1024) {
        int c = hist[b];
        blockbase[blk * NBUK + b] = c ? atomicAdd(&bucketcnt[b], c) : 0;
    }
}

__global__ __launch_bounds__(256) void scan_block_kernel(
    const int* __restrict__ deg, int* __restrict__ off, int* __restrict__ aux, int n)
{
    __shared__ int s[256];
    int tid = threadIdx.x;
    int i = blockIdx.x * 256 + tid;
    int x = (i < n) ? deg[i] : 0;
    s[tid] = x;
    __syncthreads();
    #pragma unroll
    for (int o = 1; o < 256; o <<= 1) {
        int t = (tid >= o) ? s[tid - o] : 0;
        __syncthreads();
        s[tid] += t;
        __syncthreads();
    }
    if (i < n) off[i + 1] = s[tid];
    if (tid == 255) aux[blockIdx.x] = s[255];
}

__global__ __launch_bounds__(512) void scan_aux_kernel(int* __restrict__ aux, int nA)
{
    __shared__ int s[512];
    int tid = threadIdx.x;
    int x = (tid < nA) ? aux[tid] : 0;
    s[tid] = x;
    __syncthreads();
    #pragma unroll
    for (int o = 1; o < 512; o <<= 1) {
        int t = (tid >= o) ? s[tid - o] : 0;
        __syncthreads();
        s[tid] += t;
        __syncthreads();
    }
    if (tid < nA) aux[tid] = s[tid] - x;  // exclusive
}

__global__ __launch_bounds__(256) void scan_add_kernel(
    int* __restrict__ off, const int* __restrict__ aux, int n)
{
    int i = blockIdx.x * 256 + threadIdx.x;
    if (i == 0) off[0] = 0;
    if (i < n) off[i + 1] += aux[i >> 8];
}

// pack 32B records to bucket-grouped positions (LDS cursors; ~0 global atomics)
__global__ __launch_bounds__(1024) void bucket_pack_kernel(
    const int* __restrict__ e_dst, const int* __restrict__ e_src,
    const float* __restrict__ e_vals, const int* __restrict__ bucket_off,
    const int* __restrict__ blockbase, unsigned* __restrict__ epk, int epb)
{
    __shared__ int cur[NBUK];
    __shared__ int base[NBUK];
    const int tid = threadIdx.x, blk = blockIdx.x;
    for (int i = tid; i < NBUK; i += 1024) {
        cur[i] = 0;
        base[i] = bucket_off[i] + blockbase[blk * NBUK + i];
    }
    __syncthreads();
    int e0 = blk * epb;
    int e1 = e0 + epb; if (e1 > N_EDGES) e1 = N_EDGES;
    for (int e = e0 + tid; e < e1; e += 1024) {
        int d = e_dst[e];
        int b = d >> 6;
        int lr = atomicAdd(&cur[b], 1);
        int pos = base[b] + lr;
        float ev[8];
        load8f(e_vals + (size_t)e * 8, ev);
        uint4 w0;
        w0.x = (unsigned)d;
        w0.y = (unsigned)e_src[e];
        w0.z = pk16(ev[0], ev[1]);
        w0.w = pk16(ev[2], ev[3]);
        uint2 w1;
        w1.x = pk16(ev[4], ev[5]);
        w1.y = pk16(ev[6], ev[7]);
        unsigned* dst = epk + (size_t)pos * 8;
        *reinterpret_cast<uint4*>(dst)     = w0;
        *reinterpret_cast<uint2*>(dst + 4) = w1;
    }
}

// in-register per-bucket counting sort by (d & 63) -> epk globally d-sorted.
// Records held in registers; __syncthreads after load loop drains vmcnt, making
// the in-place permutation safe. Overflow (cnt > SCAP, ~16 sigma): mark DFLAG,
// edge_frag forces atomics for flagged runs.
__global__ __launch_bounds__(256) void sort_bucket_kernel(
    unsigned* __restrict__ epk, const int* __restrict__ bucket_off)
{
    __shared__ int h[BNODES];
    __shared__ int basec[BNODES];
    const int tid = threadIdx.x, bk = blockIdx.x;
    const int beg = bucket_off[bk];
    const int cnt = bucket_off[bk + 1] - beg;
    if (cnt <= 0) return;
    if (cnt > SCAP) {
        for (int i = tid; i < cnt; i += 256)
            epk[(size_t)(beg + i) * 8] |= DFLAG;
        return;
    }
    if (tid < BNODES) h[tid] = 0;
    __syncthreads();

    uint4 rA[SCAP_PT]; uint2 rB[SCAP_PT];
    #pragma unroll
    for (int k = 0; k < SCAP_PT; ++k) {
        int i = tid + k * 256;
        if (i < cnt) {
            const unsigned* ep = epk + (size_t)(beg + i) * 8;
            rA[k] = *reinterpret_cast<const uint4*>(ep);
            rB[k] = *reinterpret_cast<const uint2*>(ep + 4);
            atomicAdd(&h[rA[k].x & (BNODES - 1)], 1);
        }
    }
    __syncthreads();          // all record loads complete; hist done
    if (tid == 0) {
        int run = 0;
        #pragma unroll
        for (int j = 0; j < BNODES; ++j) { basec[j] = run; run += h[j]; }
    }
    __syncthreads();
    if (tid < BNODES) h[tid] = 0;   // reuse as cursors
    __syncthreads();
    #pragma unroll
    for (int k = 0; k < SCAP_PT; ++k) {
        int i = tid + k * 256;
        if (i < cnt) {
            int d6 = rA[k].x & (BNODES - 1);
            int p = basec[d6] + atomicAdd(&h[d6], 1);
            unsigned* dst = epk + (size_t)(beg + p) * 8;
            *reinterpret_cast<uint4*>(dst)     = rA[k];
            *reinterpret_cast<uint2*>(dst + 4) = rB[k];
        }
    }
}

// ---- edge kernel (r8 proven): fragment-direct h1 + MFMA W2 + segmented reduce
//      over bf16 h2; flag-aware (DFLAG runs always use atomics) ----------------

__global__ __launch_bounds__(256) void edge_frag_kernel(
    const float* __restrict__ A, const float* __restrict__ B,
    const unsigned* __restrict__ epk,
    const float* __restrict__ g_w1, const float* __restrict__ g_w2,
    const float* __restrict__ g_b2, float* __restrict__ agg)
{
    __shared__ unsigned s_w2[32 * 33];
    __shared__ __align__(16) unsigned s_w1e[4 * 64];
    __shared__ unsigned s_h2[256 * 17];
    __shared__ int s_d[256];
    __shared__ int s_heads[256];
    __shared__ int s_cnt, s_prevd, s_nextd;

    const int tid = threadIdx.x;
    const long bP = (long)blockIdx.x * 256;

    #pragma unroll
    for (int i = 0; i < 4; ++i) {
        int idx = tid + i * 256;
        int kp = idx >> 5, n = idx & 31;
        s_w2[kp * 33 + n] = pk16(g_w2[(2*kp)*32 + n], g_w2[(2*kp+1)*32 + n]);
    }
    {
        int i2 = tid >> 6, c = tid & 63;
        s_w1e[i2 * 64 + c] = pk16(g_w1[(64 + 2*i2)*64 + c], g_w1[(64 + 2*i2 + 1)*64 + c]);
    }
    if (tid == 0) {
        s_cnt = 0;
        s_prevd = (bP > 0) ? (int)epk[(size_t)(bP - 1) * 8] : -2;
        s_nextd = (bP + 256 < (long)N_EDGES) ? (int)epk[(size_t)(bP + 256) * 8] : -2;
    }

    const int wv   = tid >> 6;
    const int lane = tid & 63;
    const int lm   = lane & 15;
    const int lg   = lane >> 4;
    const long wP  = bP + wv * 64;

    int dM[4], sM[4];
    unsigned evp[4][4];
    #pragma unroll
    for (int mt = 0; mt < 4; ++mt) {
        long pe = wP + mt*16 + lm;
        if (pe < (long)N_EDGES) {
            const unsigned* ep = epk + (size_t)pe * 8;
            uint4 w0 = *reinterpret_cast<const uint4*>(ep);
            uint2 w1 = *reinterpret_cast<const uint2*>(ep + 4);
            dM[mt] = (int)w0.x; sM[mt] = (int)w0.y;
            evp[mt][0] = w0.z; evp[mt][1] = w0.w; evp[mt][2] = w1.x; evp[mt][3] = w1.y;
        } else {
            dM[mt] = -1; sM[mt] = 0;
            evp[mt][0] = evp[mt][1] = evp[mt][2] = evp[mt][3] = 0;
        }
        if (lg == 0) s_d[wv*64 + mt*16 + lm] = dM[mt];
    }
    __syncthreads();   // barrier 1: s_d + W staging complete

    if (bP + tid < (long)N_EDGES) {
        int d_me  = s_d[tid];
        int prevd = (tid == 0) ? s_prevd : s_d[tid - 1];
        bool true_head = (prevd != d_me);
        bool is_head = (tid == 0) || true_head;
        if (is_head) {
            int idx = atomicAdd(&s_cnt, 1);
            s_heads[idx] = tid | (true_head ? 0x10000 : 0);
        }
    }

    // ---- h1 in MFMA A-fragment registers ----
    uint4 afr[4][2];
    #pragma unroll
    for (int kt = 0; kt < 2; ++kt) {
        float acc[4][8];
        #pragma unroll
        for (int mt = 0; mt < 4; ++mt) {
            if (dM[mt] >= 0) {
                size_t dn = (size_t)(dM[mt] & 0x0FFFFFFF);
                const float4* Ap = reinterpret_cast<const float4*>(A + dn*64 + kt*32 + lg*8);
                const float4* Bp = reinterpret_cast<const float4*>(B + (size_t)sM[mt]*64 + kt*32 + lg*8);
                float4 a0 = Ap[0], a1 = Ap[1], b0 = Bp[0], b1 = Bp[1];
                acc[mt][0] = a0.x + b0.x; acc[mt][1] = a0.y + b0.y;
                acc[mt][2] = a0.z + b0.z; acc[mt][3] = a0.w + b0.w;
                acc[mt][4] = a1.x + b1.x; acc[mt][5] = a1.y + b1.y;
                acc[mt][6] = a1.z + b1.z; acc[mt][7] = a1.w + b1.w;
            } else {
                #pragma unroll
                for (int j = 0; j < 8; ++j) acc[mt][j] = 0.f;
            }
        }
        #pragma unroll
        for (int i2 = 0; i2 < 4; ++i2) {
            uint4 wA = *reinterpret_cast<const uint4*>(&s_w1e[i2*64 + kt*32 + lg*8]);
            uint4 wB = *reinterpret_cast<const uint4*>(&s_w1e[i2*64 + kt*32 + lg*8 + 4]);
            #pragma unroll
            for (int mt = 0; mt < 4; ++mt) {
                unsigned e2 = evp[mt][i2];
                acc[mt][0] = fdot2f(e2, wA.x, acc[mt][0]);
                acc[mt][1] = fdot2f(e2, wA.y, acc[mt][1]);
                acc[mt][2] = fdot2f(e2, wA.z, acc[mt][2]);
                acc[mt][3] = fdot2f(e2, wA.w, acc[mt][3]);
                acc[mt][4] = fdot2f(e2, wB.x, acc[mt][4]);
                acc[mt][5] = fdot2f(e2, wB.y, acc[mt][5]);
                acc[mt][6] = fdot2f(e2, wB.z, acc[mt][6]);
                acc[mt][7] = fdot2f(e2, wB.w, acc[mt][7]);
            }
        }
        #pragma unroll
        for (int mt = 0; mt < 4; ++mt) {
            uint4 w;
            w.x = pk16(fmaxf(acc[mt][0], 0.f), fmaxf(acc[mt][1], 0.f));
            w.y = pk16(fmaxf(acc[mt][2], 0.f), fmaxf(acc[mt][3], 0.f));
            w.z = pk16(fmaxf(acc[mt][4], 0.f), fmaxf(acc[mt][5], 0.f));
            w.w = pk16(fmaxf(acc[mt][6], 0.f), fmaxf(acc[mt][7], 0.f));
            afr[mt][kt] = w;
        }
    }

    // ---- MFMA: [64 edges x 64] @ [64 x 32] ----
    f32x4 mac[4][2];
    #pragma unroll
    for (int mt = 0; mt < 4; ++mt) {
        #pragma unroll
        for (int nt = 0; nt < 2; ++nt) {
            mac[mt][nt][0] = 0.f; mac[mt][nt][1] = 0.f;
            mac[mt][nt][2] = 0.f; mac[mt][nt][3] = 0.f;
        }
    }
    #pragma unroll
    for (int kt = 0; kt < 2; ++kt) {
        uint4 bf0, bf1;
        int kp = kt*16 + lg*4;
        bf0.x = s_w2[(kp+0)*33 + lm];      bf1.x = s_w2[(kp+0)*33 + 16 + lm];
        bf0.y = s_w2[(kp+1)*33 + lm];      bf1.y = s_w2[(kp+1)*33 + 16 + lm];
        bf0.z = s_w2[(kp+2)*33 + lm];      bf1.z = s_w2[(kp+2)*33 + 16 + lm];
        bf0.w = s_w2[(kp+3)*33 + lm];      bf1.w = s_w2[(kp+3)*33 + 16 + lm];
        f16x8 b0 = as_f16x8(bf0), b1 = as_f16x8(bf1);
        #pragma unroll
        for (int mt = 0; mt < 4; ++mt) {
            f16x8 a = as_f16x8(afr[mt][kt]);
            mac[mt][0] = __builtin_amdgcn_mfma_f32_16x16x32_f16(a, b0, mac[mt][0], 0, 0, 0);
            mac[mt][1] = __builtin_amdgcn_mfma_f32_16x16x32_f16(a, b1, mac[mt][1], 0, 0, 0);
        }
    }

    // ---- write h2 = relu(mac + b2) as packed bf16 to LDS ----
    float b2a = g_b2[lm], b2b = g_b2[16 + lm];
    unsigned short* h2s = reinterpret_cast<unsigned short*>(s_h2);
    #pragma unroll
    for (int mt = 0; mt < 4; ++mt) {
        #pragma unroll
        for (int r = 0; r < 4; ++r) {
            int edge = wv*64 + mt*16 + lg*4 + r;
            h2s[edge*34 + lm]      = bf16_1(fmaxf(mac[mt][0][r] + b2a, 0.f));
            h2s[edge*34 + 16 + lm] = bf16_1(fmaxf(mac[mt][1][r] + b2b, 0.f));
        }
    }
    __syncthreads();   // barrier 2: h2 + heads ready

    // ---- segmented reduce (16 channel-pairs per segment) ----
    const int nseg = s_cnt;
    const int next_d = s_nextd;
    for (int w = tid; w < nseg * 16; w += 256) {
        int seg = w >> 4, cp = w & 15;
        int ent = s_heads[seg];
        int h = ent & 0xFFFF;
        bool thead = (ent & 0x10000) != 0;
        int dd = s_d[h];
        float s0 = 0.f, s1 = 0.f;
        int r = h;
        while (r < 256 && s_d[r] == dd) {
            unsigned x = s_h2[r*17 + cp];
            s0 += __uint_as_float(x << 16);
            s1 += __uint_as_float(x & 0xFFFF0000u);
            ++r;
        }
        bool end_complete = (r < 256) || (next_d != dd);
        int node = dd & 0x0FFFFFFF;
        bool flg = (dd & DFLAG) != 0;
        float* dst = agg + (size_t)node * 32 + 2 * cp;
        if (thead && end_complete && !flg) {
            *reinterpret_cast<float2*>(dst) = make_float2(s0, s1);  // sole writer
        } else {
            atomicAdd(dst + 0, s0);
            atomicAdd(dst + 1, s1);
        }
    }
}

// ---------------- node MLP (reads agg) -----------------------------------------

__global__ __launch_bounds__(256) void node_kernel(
    const float* __restrict__ u, const float* __restrict__ agg,
    const float* __restrict__ f_w1, const float* __restrict__ f_b1,
    const float* __restrict__ f_w2, const float* __restrict__ f_b2,
    const float* __restrict__ t_w, const float* __restrict__ t_b,
    float* __restrict__ out)
{
    int n = blockIdx.x * 256 + threadIdx.x;
    if (n >= U_NODES) return;
    float x[64];
    load32f(u   + (size_t)n * 32, x);
    load32f(agg + (size_t)n * 32, x + 32);
    float z1[64];
    #pragma unroll
    for (int j = 0; j < 64; ++j) z1[j] = f_b1[j];
    #pragma unroll
    for (int i = 0; i < 64; ++i) {
        #pragma unroll
        for (int j = 0; j < 64; ++j) z1[j] += x[i] * f_w1[i*64 + j];
    }
    #pragma unroll
    for (int j = 0; j < 64; ++j) z1[j] = fmaxf(z1[j], 0.f);
    float z2[32];
    #pragma unroll
    for (int k = 0; k < 32; ++k) z2[k] = f_b2[k];
    #pragma unroll
    for (int j = 0; j < 64; ++j) {
        #pragma unroll
        for (int k = 0; k < 32; ++k) z2[k] += z1[j] * f_w2[j*32 + k];
    }
    #pragma unroll
    for (int k = 0; k < 32; ++k) z2[k] = fmaxf(z2[k], 0.f);
    float o = t_b[0];
    #pragma unroll
    for (int k = 0; k < 32; ++k) o += z2[k] * t_w[k];
    out[n] = 1.f / (1.f + expf(-o));
}

// ---------------- fallbacks for small workspaces -------------------------------

__global__ __launch_bounds__(256) void rank_kernel(
    const int* __restrict__ e_dst, int* __restrict__ deg, int* __restrict__ rank)
{
    int e = blockIdx.x * 256 + threadIdx.x;
    if (e >= N_EDGES) return;
    rank[e] = atomicAdd(&deg[e_dst[e]], 1);
}

__global__ __launch_bounds__(256) void scatter_kernel(
    const int* __restrict__ e_dst, const int* __restrict__ off,
    const int* __restrict__ rank, int* __restrict__ sorted_eid)
{
    int e = blockIdx.x * 256 + threadIdx.x;
    if (e >= N_EDGES) return;
    int d = e_dst[e];
    sorted_eid[off[d] + rank[e]] = e;
}

template <bool HAS_A, bool HAS_B>
__global__ __launch_bounds__(256) void edge_sorted_kernel(
    const float* __restrict__ A, const float* __restrict__ B,
    const float* __restrict__ u, const float* __restrict__ v,
    const float* __restrict__ e_vals, const int* __restrict__ e_src,
    const int* __restrict__ e_dst, const int* __restrict__ seid,
    const float* __restrict__ g_w1, const float* __restrict__ g_b1,
    const float* __restrict__ g_w2, const float* __restrict__ g_b2,
    float* __restrict__ agg)
{
    __shared__ unsigned lds_h[256][17];
    __shared__ int lds_d[256];
    __shared__ int lds_heads[256];
    __shared__ int lds_cnt;
    __shared__ int lds_prev_d, lds_next_d;

    const int tid = threadIdx.x;
    const long p = (long)blockIdx.x * 256 + tid;

    if (tid == 0) {
        lds_cnt = 0;
        long pprev = (long)blockIdx.x * 256 - 1;
        lds_prev_d = (pprev < 0) ? -2 : e_dst[seid[pprev]];
        long pnext = (long)blockIdx.x * 256 + 256;
        lds_next_d = (pnext >= N_EDGES) ? -2 : e_dst[seid[pnext]];
    }

    int d = -1;
    if (p < N_EDGES) {
        int eid = seid[p];
        d = e_dst[eid];
        int s = e_src[eid];

        float h1[64];
        if constexpr (HAS_A) {
            const float4* Ap = reinterpret_cast<const float4*>(A + (size_t)d * 64);
            #pragma unroll
            for (int q = 0; q < 16; ++q) {
                float4 a = Ap[q];
                h1[4*q+0] = a.x; h1[4*q+1] = a.y; h1[4*q+2] = a.z; h1[4*q+3] = a.w;
            }
        } else {
            #pragma unroll
            for (int j = 0; j < 64; ++j) h1[j] = 0.f;
            float x[32];
            load32f(u + (size_t)d * 32, x);
            #pragma unroll
            for (int i = 0; i < 32; ++i) {
                #pragma unroll
                for (int j = 0; j < 64; ++j) h1[j] += x[i] * g_w1[i*64 + j];
            }
        }
        if constexpr (HAS_B) {
            const float4* Bp = reinterpret_cast<const float4*>(B + (size_t)s * 64);
            #pragma unroll
            for (int q = 0; q < 16; ++q) {
                float4 b = Bp[q];
                h1[4*q+0] += b.x; h1[4*q+1] += b.y; h1[4*q+2] += b.z; h1[4*q+3] += b.w;
            }
        } else {
            #pragma unroll
            for (int j = 0; j < 64; ++j) h1[j] += g_b1[j];
            float x[32];
            load32f(v + (size_t)s * 32, x);
            #pragma unroll
            for (int i = 0; i < 32; ++i) {
                #pragma unroll
                for (int j = 0; j < 64; ++j) h1[j] += x[i] * g_w1[(32+i)*64 + j];
            }
        }
        float ev[8];
        load8f(e_vals + (size_t)eid * 8, ev);
        #pragma unroll
        for (int i = 0; i < 8; ++i) {
            #pragma unroll
            for (int j = 0; j < 64; ++j) h1[j] += ev[i] * g_w1[(64+i)*64 + j];
        }
        #pragma unroll
        for (int j = 0; j < 64; ++j) h1[j] = fmaxf(h1[j], 0.f);

        float h2[32];
        #pragma unroll
        for (int k = 0; k < 32; ++k) h2[k] = g_b2[k];
        #pragma unroll
        for (int i = 0; i < 64; ++i) {
            #pragma unroll
            for (int k = 0; k < 32; ++k) h2[k] += h1[i] * g_w2[i*32 + k];
        }
        #pragma unroll
        for (int cp = 0; cp < 16; ++cp)
            lds_h[tid][cp] = pack_bf16x2(fmaxf(h2[2*cp], 0.f), fmaxf(h2[2*cp+1], 0.f));
    }
    lds_d[tid] = d;
    __syncthreads();

    if (p < N_EDGES) {
        int prevd = (tid == 0) ? lds_prev_d : lds_d[tid - 1];
        bool true_head = (prevd != d);
        bool is_head = (tid == 0) || true_head;
        if (is_head) {
            int idx = atomicAdd(&lds_cnt, 1);
            lds_heads[idx] = tid | (true_head ? 0x10000 : 0);
        }
    }
    __syncthreads();

    const int nseg = lds_cnt;
    const int next_d = lds_next_d;
    for (int w = tid; w < nseg * 16; w += 256) {
        int seg = w >> 4, cp = w & 15;
        int ent = lds_heads[seg];
        int h = ent & 0xFFFF;
        bool thead = (ent & 0x10000) != 0;
        int dd = lds_d[h];
        float s0 = 0.f, s1 = 0.f;
        int r = h;
        while (r < 256 && lds_d[r] == dd) {
            unsigned x = lds_h[r][cp];
            s0 += __uint_as_float(x << 16);
            s1 += __uint_as_float(x & 0xFFFF0000u);
            ++r;
        }
        bool end_complete = (r < 256) || (next_d != dd);
        float* dst = agg + (size_t)dd * 32 + 2 * cp;
        if (thead && end_complete) {
            *reinterpret_cast<float2*>(dst) = make_float2(s0, s1);
        } else {
            atomicAdd(dst + 0, s0);
            atomicAdd(dst + 1, s1);
        }
    }
}

__global__ __launch_bounds__(256) void edge_direct_kernel(
    const float* __restrict__ u, const float* __restrict__ v,
    const float* __restrict__ e_vals, const int* __restrict__ e_src,
    const int* __restrict__ e_dst, const float* __restrict__ g_w1,
    const float* __restrict__ g_b1, const float* __restrict__ g_w2,
    const float* __restrict__ g_b2, float* __restrict__ agg)
{
    int e = blockIdx.x * 256 + threadIdx.x;
    if (e >= N_EDGES) return;
    int d = e_dst[e];
    int s = e_src[e];
    float x[72];
    load32f(u + (size_t)d * 32, x);
    load32f(v + (size_t)s * 32, x + 32);
    load8f(e_vals + (size_t)e * 8, x + 64);
    float h1[64];
    #pragma unroll
    for (int j = 0; j < 64; ++j) h1[j] = g_b1[j];
    #pragma unroll
    for (int i = 0; i < 72; ++i) {
        #pragma unroll
        for (int j = 0; j < 64; ++j) h1[j] += x[i] * g_w1[i*64 + j];
    }
    #pragma unroll
    for (int j = 0; j < 64; ++j) h1[j] = fmaxf(h1[j], 0.f);
    float acc2[32];
    #pragma unroll
    for (int k = 0; k < 32; ++k) acc2[k] = g_b2[k];
    #pragma unroll
    for (int i = 0; i < 64; ++i) {
        #pragma unroll
        for (int k = 0; k < 32; ++k) acc2[k] += h1[i] * g_w2[i*32 + k];
    }
    float* aggp = agg + (size_t)d * 32;
    #pragma unroll
    for (int k = 0; k < 32; ++k) atomicAdd(aggp + k, fmaxf(acc2[k], 0.f));
}

// ---------------- launch -------------------------------------------------------

static inline size_t align256(size_t x) { return (x + 255) & ~(size_t)255; }

extern "C" void kernel_launch(void* const* d_in, const int* in_sizes, int n_in,
                              void* d_out, int out_size, void* d_ws, size_t ws_size,
                              hipStream_t stream) {
    const float* u      = (const float*)d_in[0];
    const float* v      = (const float*)d_in[1];
    const float* e_vals = (const float*)d_in[2];
    const int*   e_src  = (const int*)  d_in[3];
    const int*   e_dst  = (const int*)  d_in[4];
    const float* g_w1   = (const float*)d_in[5];
    const float* g_b1   = (const float*)d_in[6];
    const float* g_w2   = (const float*)d_in[7];
    const float* g_b2   = (const float*)d_in[8];
    const float* f_w1   = (const float*)d_in[9];
    const float* f_b1   = (const float*)d_in[10];
    const float* f_w2   = (const float*)d_in[11];
    const float* f_b2   = (const float*)d_in[12];
    const float* t_w    = (const float*)d_in[13];
    const float* t_b    = (const float*)d_in[14];
    float* out = (float*)d_out;

    char* wsc = (char*)d_ws;
    const int eBlocks = (N_EDGES + 255) / 256;
    const int nChunksB = (NBUK + 255) / 256;

    const size_t bcB   = align256((size_t)NBUK * 4);
    const size_t boB   = align256((size_t)(NBUK + 1) * 4);
    const size_t auxB  = align256((size_t)nChunksB * 4);
    const size_t aggB  = align256((size_t)U_NODES * 32 * 4);      // 12.8 MB
    const size_t epkB  = align256((size_t)N_EDGES * 32);          // 64 MB
    const size_t bB    = align256((size_t)V_NODES * 64 * 4);      // 12.8 MB
    const size_t aB    = align256((size_t)U_NODES * 64 * 4);      // 25.6 MB
    const size_t e4B   = align256((size_t)N_EDGES * 4);           // 8 MB

    // bucket-path layout; blockbase sized for HB blocks (chosen below)
    auto layoutNeed = [&](int hb, size_t* offs) -> size_t {
        size_t bbB = align256((size_t)hb * NBUK * 4);
        size_t o = 0;
        offs[0] = o; o += bcB;    // bucketcnt
        offs[1] = o; o += boB;    // bucketoff
        offs[2] = o; o += auxB;   // aux
        offs[3] = o; o += bbB;    // blockbase
        offs[4] = o; o += aggB;   // agg
        offs[5] = o; o += epkB;   // epk
        offs[6] = o; o += bB;     // B
        offs[7] = o; o += aB;     // A
        return o;
    };
    size_t offs256[8], offs128[8];
    size_t need256 = layoutNeed(256, offs256);
    size_t need128 = layoutNeed(128, offs128);

    // fallback layouts
    const size_t degB = align256((size_t)U_NODES * 4);
    const size_t offB = align256((size_t)(U_NODES + 1) * 4);
    const int nChunksU = (U_NODES + 255) / 256;
    const size_t auxUB = align256((size_t)nChunksU * 4);
    size_t o3 = 0;
    size_t oDeg3 = o3; o3 += degB;
    size_t oOff3 = o3; o3 += offB;
    size_t oAux3 = o3; o3 += auxUB;
    size_t oAgg3 = o3; o3 += aggB;
    size_t oSeid = o3; o3 += e4B;
    size_t needT4 = o3 + e4B;
    size_t oB3 = o3;   o3 += bB;
    size_t oA3 = o3;   o3 += aB;
    size_t needT3 = o3;

    if (ws_size >= need128) {
        const int HBn = (ws_size >= need256) ? 256 : 128;
        const size_t* of = (ws_size >= need256) ? offs256 : offs128;
        const int epb = (N_EDGES + HBn - 1) / HBn;

        int* bucketcnt = (int*)(wsc + of[0]);
        int* bucketoff = (int*)(wsc + of[1]);
        int* aux       = (int*)(wsc + of[2]);
        int* blockbase = (int*)(wsc + of[3]);
        float* agg     = (float*)(wsc + of[4]);
        unsigned* epk  = (unsigned*)(wsc + of[5]);
        float* B       = (float*)(wsc + of[6]);
        float* A       = (float*)(wsc + of[7]);

        hipMemsetAsync(bucketcnt, 0, (size_t)NBUK * 4, stream);
        hipMemsetAsync(agg, 0, (size_t)U_NODES * 32 * 4, stream);

        bucket_hist_kernel<<<HBn, 1024, 0, stream>>>(e_dst, bucketcnt, blockbase, epb);
        scan_block_kernel<<<nChunksB, 256, 0, stream>>>(bucketcnt, bucketoff, aux, NBUK);
        scan_aux_kernel<<<1, 512, 0, stream>>>(aux, nChunksB);
        scan_add_kernel<<<nChunksB, 256, 0, stream>>>(bucketoff, aux, NBUK);
        bucket_pack_kernel<<<HBn, 1024, 0, stream>>>(e_dst, e_src, e_vals,
                                                     bucketoff, blockbase, epk, epb);
        sort_bucket_kernel<<<NBUK, 256, 0, stream>>>(epk, bucketoff);
        proj_v_kernel<<<VBLKS, 256, 0, stream>>>(v, g_w1, g_b1, B);
        proj_u_kernel<<<UBLKS, 256, 0, stream>>>(u, g_w1, A);
        edge_frag_kernel<<<eBlocks, 256, 0, stream>>>(A, B, epk, g_w1, g_w2, g_b2, agg);
        node_kernel<<<UBLKS, 256, 0, stream>>>(
            u, agg, f_w1, f_b1, f_w2, f_b2, t_w, t_b, out);
    } else if (ws_size >= needT4) {
        const bool hasAB = (ws_size >= needT3);
        int* deg   = (int*)(wsc + oDeg3);
        int* off   = (int*)(wsc + oOff3);
        int* aux   = (int*)(wsc + oAux3);
        float* agg = (float*)(wsc + oAgg3);
        int* seid  = (int*)(wsc + oSeid);
        float* B = hasAB ? (float*)(wsc + oB3) : nullptr;
        float* A = hasAB ? (float*)(wsc + oA3) : nullptr;
        int* rank = hasAB ? (int*)A : (int*)(wsc + oSeid + e4B);

        hipMemsetAsync(deg, 0, (size_t)U_NODES * 4, stream);
        hipMemsetAsync(agg, 0, (size_t)U_NODES * 32 * 4, stream);

        rank_kernel<<<eBlocks, 256, 0, stream>>>(e_dst, deg, rank);
        scan_block_kernel<<<nChunksU, 256, 0, stream>>>(deg, off, aux, U_NODES);
        scan_aux_kernel<<<1, 512, 0, stream>>>(aux, nChunksU);
        scan_add_kernel<<<nChunksU, 256, 0, stream>>>(off, aux, U_NODES);
        scatter_kernel<<<eBlocks, 256, 0, stream>>>(e_dst, off, rank, seid);

        if (hasAB) {
            proj_v_kernel<<<VBLKS, 256, 0, stream>>>(v, g_w1, g_b1, B);
            proj_u_kernel<<<UBLKS, 256, 0, stream>>>(u, g_w1, A);
            edge_sorted_kernel<true, true><<<eBlocks, 256, 0, stream>>>(
                A, B, u, v, e_vals, e_src, e_dst, seid, g_w1, g_b1, g_w2, g_b2, agg);
        } else {
            edge_sorted_kernel<false, false><<<eBlocks, 256, 0, stream>>>(
                nullptr, nullptr, u, v, e_vals, e_src, e_dst, seid,
                g_w1, g_b1, g_w2, g_b2, agg);
        }
        node_kernel<<<UBLKS, 256, 0, stream>>>(
            u, agg, f_w1, f_b1, f_w2, f_b2, t_w, t_b, out);
    } else {
        float* agg0 = (float*)wsc;
        hipMemsetAsync(agg0, 0, (size_t)U_NODES * 32 * 4, stream);
        edge_direct_kernel<<<eBlocks, 256, 0, stream>>>(
            u, v, e_vals, e_src, e_dst, g_w1, g_b1, g_w2, g_b2, agg0);
        node_kernel<<<UBLKS, 256, 0, stream>>>(
            u, agg0, f_w1, f_b1, f_w2, f_b2, t_w, t_b, out);
    }
}